// Round 15
// baseline (156.367 us; speedup 1.0000x reference)
//
#include <hip/hip_runtime.h>

// CCAMDec: out = x + scale * softmax(max_k(E)-E) @ y,  E = x·yᵀ over HW
// N=8, C=512, K=64, HW=4096. softmax(max-E) == softmax(-E) (shift invariance).
#define N_ 8
#define C_ 512
#define K_ 64
#define HW_ 4096
#define NSP 8                   // s-splits per (n,ct)
#define SRANGE (HW_ / NSP)      // 512 s per k_esm block
#define SCHUNK 128              // s per staged chunk
#define NCH (SRANGE / SCHUNK)   // 4 chunks per block

typedef __attribute__((ext_vector_type(8))) short short8;   // 8 bf16 (4 VGPRs) MFMA A/B frag
typedef __attribute__((ext_vector_type(4))) float floatx4;  // MFMA C/D frag

// 8 f32 -> 8 bf16 via hardware v_cvt_pk_bf16_f32 (RNE, 1 instr / 2 elems)
__device__ __forceinline__ short8 cvt8(const float* __restrict__ p){
  float4 u = *(const float4*)p;
  float4 w = *(const float4*)(p + 4);
  union { unsigned u32[4]; short8 s; } r;
  asm("v_cvt_pk_bf16_f32 %0, %1, %2" : "=v"(r.u32[0]) : "v"(u.x), "v"(u.y));
  asm("v_cvt_pk_bf16_f32 %0, %1, %2" : "=v"(r.u32[1]) : "v"(u.z), "v"(u.w));
  asm("v_cvt_pk_bf16_f32 %0, %1, %2" : "=v"(r.u32[2]) : "v"(w.x), "v"(w.y));
  asm("v_cvt_pk_bf16_f32 %0, %1, %2" : "=v"(r.u32[3]) : "v"(w.z), "v"(w.w));
  return r.s;
}

// async global -> LDS, 16 B/lane (1 KB/wave), zero VGPR cost
__device__ __forceinline__ void gload16(const void* g, void* l){
  __builtin_amdgcn_global_load_lds(
      (const __attribute__((address_space(1))) void*)g,
      (__attribute__((address_space(3))) void*)l, 16, 0, 0);
}

// K0: y (f32, [n][k][s]) -> ybf (bf16 row-major [n][k][s]) and ytr (bf16 [n][s][k])
__global__ __launch_bounds__(256) void k_prep(const float* __restrict__ y,
                                              unsigned short* __restrict__ ybf,
                                              unsigned short* __restrict__ ytr){
  __shared__ unsigned short tile[64][72];
  int n  = blockIdx.x >> 6;                 // 64 s-tiles per batch
  int s0 = (blockIdx.x & 63) << 6;
  int tid = threadIdx.x;
  int k  = tid >> 2;
  int sc = (tid & 3) << 4;
  const float* yp = y + ((size_t)n * K_ + k) * HW_ + s0 + sc;
  union { unsigned short u16[16]; short8 s8[2]; uint4 q[2]; } u;
  u.s8[0] = cvt8(yp);
  u.s8[1] = cvt8(yp + 8);
  unsigned short* rp = ybf + ((size_t)n * K_ + k) * HW_ + s0 + sc;
  *(uint4*)rp       = u.q[0];
  *(uint4*)(rp + 8) = u.q[1];
#pragma unroll
  for (int j = 0; j < 16; ++j) tile[sc + j][k] = u.u16[j];
  __syncthreads();
  int s  = tid >> 2;
  int kc = (tid & 3) << 4;
  unsigned short* tp = ytr + ((size_t)n * HW_ + s0 + s) * K_ + kc;
  *(uint4*)tp       = *(const uint4*)&tile[s][kc];
  *(uint4*)(tp + 8) = *(const uint4*)&tile[s][kc + 8];
}

// K1: energy + last-block softmax.  Block = (n, 16c, 512s), 4 waves,
// 4 chunks of 128s, 2-buffer gload_lds + counted vmcnt(6) (R10 core).
// Wave w owns s-slice w of each chunk, all 4 k-quadrants (acc[4]).
// Epilogue: intra-block LDS reduce -> ONE plain float4 store per thread
// into a PRIVATE 4KB slot (no RMW) -> one ticket atomicAdd per block; the
// LAST of the 8 sp-blocks reads the 8 slots (agent-scope atomic loads),
// does softmax(-E), writes att.  No spinning, ~2K RMWs total (R14 lesson:
// 1M atomicAdds = 60+ us; private slots + ticket = free).
__global__ __launch_bounds__(256) void k_esm(const float* __restrict__ x,
                                             const unsigned short* __restrict__ ybf,
                                             float* __restrict__ epart,
                                             unsigned* __restrict__ cnt,
                                             unsigned short* __restrict__ att){
  __shared__ char smem[49152];
  __shared__ unsigned tk;
  const int bid = ((blockIdx.x & 7) << 8) | (blockIdx.x >> 3);  // XCD swizzle (2048%8==0)
  const int sp = bid & 7;
  const int ct = (bid >> 3) & 31;
  const int n  = bid >> 8;
  const int tid = threadIdx.x;
  const int w = tid >> 6, l = tid & 63;
  const int lo = l & 15, hi = l >> 4;
  const int c0 = ct << 4;
  const int sb = sp * SRANGE;
  const int pg = (n << 5) + ct;

  // chunk-invariant per-lane source addresses (bytes), pre-swizzled
  const int ar0 = ((w << 1) + 0) * 2 + (l >> 5);
  const int ar1 = ((w << 1) + 1) * 2 + (l >> 5);
  const char* asrc0 = (const char*)(x + ((size_t)n * C_ + c0 + ar0) * HW_ + sb)
                      + ((16 * (l & 31)) ^ ((ar0 & 7) << 4));
  const char* asrc1 = (const char*)(x + ((size_t)n * C_ + c0 + ar1) * HW_ + sb)
                      + ((16 * (l & 31)) ^ ((ar1 & 7) << 4));
  const char* bsrc[4];
#pragma unroll
  for (int j = 0; j < 4; ++j){
    int kk = ((w << 2) + j) * 4 + (l >> 4);
    bsrc[j] = (const char*)(ybf + ((size_t)n * K_ + kk) * HW_ + sb)
              + ((16 * (l & 15)) ^ ((kk & 7) << 4));
  }

  floatx4 acc[4];
#pragma unroll
  for (int q = 0; q < 4; ++q) acc[q] = (floatx4){0.f, 0.f, 0.f, 0.f};
  const int aswz = (lo & 7) << 4;

#define AS(BUF) (smem + (BUF) * 24576)
#define BS(BUF) (smem + (BUF) * 24576 + 8192)
#define STAGE(BUF, CH)                                                         \
  {                                                                            \
    gload16(asrc0 + (size_t)(CH) * (SCHUNK * 4), AS(BUF) + (((w << 1) + 0) << 10)); \
    gload16(asrc1 + (size_t)(CH) * (SCHUNK * 4), AS(BUF) + (((w << 1) + 1) << 10)); \
    _Pragma("unroll")                                                          \
    for (int j = 0; j < 4; ++j)                                                \
      gload16(bsrc[j] + (size_t)(CH) * (SCHUNK * 2), BS(BUF) + (((w << 2) + j) << 10)); \
  }

  STAGE(0, 0)

#pragma unroll
  for (int ch = 0; ch < NCH; ++ch){
    const int cur = ch & 1;
    if (ch + 1 < NCH){
      STAGE(cur ^ 1, ch + 1)
      asm volatile("s_waitcnt vmcnt(6)" ::: "memory");   // chunk ch complete
    } else {
      asm volatile("s_waitcnt vmcnt(0)" ::: "memory");
    }
    __builtin_amdgcn_s_barrier();
    __builtin_amdgcn_sched_barrier(0);
    {
      // wave's own s-slice (32 s of the 128-s chunk)
      int ao = (w << 7) + (hi << 5);
      const char* ab = AS(cur) + (lo << 9);
      float4 a0f = *(const float4*)(ab + ((ao     ) ^ aswz));
      float4 a1f = *(const float4*)(ab + ((ao + 16) ^ aswz));
      union { unsigned u32[4]; short8 s; } af;
      asm("v_cvt_pk_bf16_f32 %0, %1, %2" : "=v"(af.u32[0]) : "v"(a0f.x), "v"(a0f.y));
      asm("v_cvt_pk_bf16_f32 %0, %1, %2" : "=v"(af.u32[1]) : "v"(a0f.z), "v"(a0f.w));
      asm("v_cvt_pk_bf16_f32 %0, %1, %2" : "=v"(af.u32[2]) : "v"(a1f.x), "v"(a1f.y));
      asm("v_cvt_pk_bf16_f32 %0, %1, %2" : "=v"(af.u32[3]) : "v"(a1f.z), "v"(a1f.w));
#pragma unroll
      for (int q = 0; q < 4; ++q){
        short8 b = *(const short8*)(BS(cur) + ((q << 4) + lo) * 256
                                    + (((w << 6) + (hi << 4)) ^ aswz));
        // swapped: A = y-frag (M=k), B = x-frag (N=c) -> D col=lo->c, row->k
        acc[q] = __builtin_amdgcn_mfma_f32_16x16x32_bf16(b, af.s, acc[q], 0, 0, 0);
      }
    }
    __builtin_amdgcn_sched_barrier(0);
    __builtin_amdgcn_s_barrier();
  }
#undef STAGE

  // ---- intra-block reduce (alias Els onto drained staging) ----
  float (*Els)[16][64] = (float (*)[16][64])smem;   // 16 KB
#pragma unroll
  for (int q = 0; q < 4; ++q)
    *(floatx4*)&Els[w][lo][(q << 4) + (hi << 2)] = acc[q];
  __syncthreads();

  {
    int c = tid >> 4, j = tid & 15;
    float4 e = *(const float4*)&Els[0][c][4 * j];
    float4 t1 = *(const float4*)&Els[1][c][4 * j];
    float4 t2 = *(const float4*)&Els[2][c][4 * j];
    float4 t3 = *(const float4*)&Els[3][c][4 * j];
    e.x += t1.x + t2.x + t3.x; e.y += t1.y + t2.y + t3.y;
    e.z += t1.z + t2.z + t3.z; e.w += t1.w + t2.w + t3.w;
    // PRIVATE slot: one plain float4 store per thread, no contention
    *(float4*)(epart + ((size_t)((pg << 3) + sp) << 10) + (tid << 2)) = e;
  }
  __syncthreads();                    // drains all stores (waitcnt 0 + barrier)
  if (tid == 0){
    __threadfence();                  // release
    tk = atomicAdd(&cnt[pg], 1u);     // ONE RMW per block
  }
  __syncthreads();
  if (tk != NSP - 1) return;          // not last -> done, no waiting

  // ---- last block: reduce 8 slots + softmax(-E) ----
  __threadfence();                    // acquire
  {
    int c = tid >> 4, j = tid & 15;
    float e0 = 0.f, e1 = 0.f, e2 = 0.f, e3 = 0.f;
#pragma unroll
    for (int sp2 = 0; sp2 < NSP; ++sp2){
      const float* src = epart + ((size_t)((pg << 3) + sp2) << 10) + (tid << 2);
      e0 += __hip_atomic_load(src + 0, __ATOMIC_RELAXED, __HIP_MEMORY_SCOPE_AGENT);
      e1 += __hip_atomic_load(src + 1, __ATOMIC_RELAXED, __HIP_MEMORY_SCOPE_AGENT);
      e2 += __hip_atomic_load(src + 2, __ATOMIC_RELAXED, __HIP_MEMORY_SCOPE_AGENT);
      e3 += __hip_atomic_load(src + 3, __ATOMIC_RELAXED, __HIP_MEMORY_SCOPE_AGENT);
    }
    float m = fminf(fminf(e0, e1), fminf(e2, e3));
#pragma unroll
    for (int off = 8; off; off >>= 1) m = fminf(m, __shfl_xor(m, off, 16));
    float p0 = __expf(m - e0), p1 = __expf(m - e1);
    float p2 = __expf(m - e2), p3 = __expf(m - e3);
    float s = p0 + p1 + p2 + p3;
#pragma unroll
    for (int off = 8; off; off >>= 1) s += __shfl_xor(s, off, 16);
    float inv = 1.f / s;
    unsigned d0, d1;
    asm("v_cvt_pk_bf16_f32 %0, %1, %2" : "=v"(d0) : "v"(p0 * inv), "v"(p1 * inv));
    asm("v_cvt_pk_bf16_f32 %0, %1, %2" : "=v"(d1) : "v"(p2 * inv), "v"(p3 * inv));
    uint2 dd; dd.x = d0; dd.y = d1;
    *(uint2*)(att + ((size_t)n * C_ + c0 + c) * K_ + 4 * j) = dd;
  }
#undef AS
#undef BS
}

// K2: out = x + scale * att @ y.  Grid 2048 (4-8 blocks/CU), 256 thr.
// att (L2-hot) -> XOR-swizzled LDS -> B frags.  Swapped MFMA, A straight
// from ytr; T[16][68] transpose -> 256B-contiguous x-load / out-store.
__global__ __launch_bounds__(256) void k_pv(const float* __restrict__ x,
                                            const unsigned short* __restrict__ att,
                                            const unsigned short* __restrict__ ytr,
                                            const float* __restrict__ scale,
                                            float* __restrict__ out){
  __shared__ float T[4][16][68];
  __shared__ char attl[2048];
  int bid = ((blockIdx.x & 7) << 8) | (blockIdx.x >> 3);  // XCD swizzle (2048%8==0)
  int sb = bid & 7;
  int ct = (bid >> 3) & 31;
  int n  = bid >> 8;
  int tid = threadIdx.x;
  int w  = tid >> 6;
  int l  = tid & 63, lo = l & 15, hi = l >> 4;
  int c0 = ct << 4;
  int sP = (sb << 9) + (w << 7);     // 512 per block, 128 per wave
  float sc = scale[0];

  {
    int c = tid >> 4, j = tid & 15;
    uint2 dd = *(const uint2*)(att + ((size_t)n * C_ + c0 + c) * K_ + 4 * j);
    *(uint2*)(attl + c * 128 + ((8 * j) ^ ((c & 7) << 4))) = dd;
  }
  __syncthreads();

  short8 batt0 = *(const short8*)(attl + lo * 128 + ((     hi * 16) ^ ((lo & 7) << 4)));
  short8 batt1 = *(const short8*)(attl + lo * 128 + ((64 + hi * 16) ^ ((lo & 7) << 4)));
  const unsigned short* ybn = ytr + (size_t)n * HW_ * K_;
  float (*Tw)[68] = T[w];
  size_t xb[4];
#pragma unroll
  for (int rg = 0; rg < 4; ++rg)
    xb[rg] = ((size_t)n * C_ + c0 + (rg << 2) + hi) * HW_ + sP + (lo << 2);

  short8 aA[8]; float4 xA[4];
  short8 aB[8]; float4 xB[4];

#define PVLOAD(G, AV, XV)                                                      \
  {                                                                            \
    int sg = sP + (G) * 64;                                                    \
    _Pragma("unroll")                                                          \
    for (int t = 0; t < 4; ++t){                                               \
      const unsigned short* ap = ybn + (size_t)(sg + t * 16 + lo) * K_ + (hi << 3); \
      AV[2 * t]     = *(const short8*)(ap);                                    \
      AV[2 * t + 1] = *(const short8*)(ap + 32);                               \
    }                                                                          \
    _Pragma("unroll")                                                          \
    for (int rg = 0; rg < 4; ++rg)                                             \
      XV[rg] = *(const float4*)(x + xb[rg] + (G) * 64);                        \
  }

#define PVCOMP(G, AV, XV)                                                      \
  {                                                                            \
    _Pragma("unroll")                                                          \
    for (int t = 0; t < 4; ++t){                                               \
      floatx4 a2 = {0.f, 0.f, 0.f, 0.f};                                       \
      a2 = __builtin_amdgcn_mfma_f32_16x16x32_bf16(AV[2 * t],     batt0, a2, 0, 0, 0); \
      a2 = __builtin_amdgcn_mfma_f32_16x16x32_bf16(AV[2 * t + 1], batt1, a2, 0, 0, 0); \
      *(floatx4*)&Tw[lo][t * 16 + (hi << 2)] = a2;   /* D: col=lo->c, row->s */ \
    }                                                                          \
    _Pragma("unroll")                                                          \
    for (int rg = 0; rg < 4; ++rg){                                            \
      float4 v  = *(const float4*)&Tw[(rg << 2) + hi][lo << 2];                \
      float4 xv = XV[rg];                                                      \
      float4 o;                                                                \
      o.x = xv.x + sc * v.x; o.y = xv.y + sc * v.y;                            \
      o.z = xv.z + sc * v.z; o.w = xv.w + sc * v.w;                            \
      *(float4*)(out + xb[rg] + (G) * 64) = o;                                 \
    }                                                                          \
  }

  PVLOAD(0, aA, xA)
  PVLOAD(1, aB, xB)
  PVCOMP(0, aA, xA)
  PVCOMP(1, aB, xB)
#undef PVLOAD
#undef PVCOMP
}

extern "C" void kernel_launch(void* const* d_in, const int* in_sizes, int n_in,
                              void* d_out, int out_size, void* d_ws, size_t ws_size,
                              hipStream_t stream){
  const float* x     = (const float*)d_in[0];
  const float* y     = (const float*)d_in[1];
  const float* scale = (const float*)d_in[2];
  float* out = (float*)d_out;

  // ws layout (17.1 MiB):
  //   epart : 2048 slots * 4 KiB = 8 MiB  @ 0      (private, no zeroing needed)
  //   cnt   : 256 u32 = 1 KiB    @ 8 MiB            (zeroed every launch)
  //   att   : N*C*K bf16 = 512 KiB @ 8 MiB + 4 KiB
  //   ybf   : N*K*HW bf16 = 4 MiB @ 9 MiB
  //   ytr   : N*HW*K bf16 = 4 MiB @ 13 MiB
  char* ws = (char*)d_ws;
  float*          epart = (float*)(ws);
  unsigned*       cnt   = (unsigned*)(ws + (8u<<20));
  unsigned short* att   = (unsigned short*)(ws + (8u<<20) + 4096);
  unsigned short* ybf   = (unsigned short*)(ws + (9u<<20));
  unsigned short* ytr   = (unsigned short*)(ws + (13u<<20));

  hipMemsetAsync(cnt, 0, 1024, stream);
  k_prep <<<N_ * (HW_/64), 256, 0, stream>>>(y, ybf, ytr);
  k_esm  <<<N_ * 32 * NSP, 256, 0, stream>>>(x, ybf, epart, cnt, att);
  k_pv   <<<N_ * 32 * 8,   256, 0, stream>>>(x, att, ytr, scale, out);
}

// Round 16
// 63.490 us; speedup vs baseline: 2.4628x; 2.4628x over previous
//
#include <hip/hip_runtime.h>

// CCAMDec: out = x + scale * softmax(max_k(E)-E) @ y,  E = x·yᵀ over HW
// N=8, C=512, K=64, HW=4096. softmax(max-E) == softmax(-E) (shift invariance).
#define N_ 8
#define C_ 512
#define K_ 64
#define HW_ 4096
#define SCHUNK 128              // s per staged chunk
#define NCH 32                  // chunks (full s = 4096)

typedef __attribute__((ext_vector_type(8))) short short8;   // 8 bf16 (4 VGPRs) MFMA A/B frag
typedef __attribute__((ext_vector_type(4))) float floatx4;  // MFMA C/D frag

// 8 f32 -> 8 bf16 via hardware v_cvt_pk_bf16_f32 (RNE, 1 instr / 2 elems)
__device__ __forceinline__ short8 cvt8(const float* __restrict__ p){
  float4 u = *(const float4*)p;
  float4 w = *(const float4*)(p + 4);
  union { unsigned u32[4]; short8 s; } r;
  asm("v_cvt_pk_bf16_f32 %0, %1, %2" : "=v"(r.u32[0]) : "v"(u.x), "v"(u.y));
  asm("v_cvt_pk_bf16_f32 %0, %1, %2" : "=v"(r.u32[1]) : "v"(u.z), "v"(u.w));
  asm("v_cvt_pk_bf16_f32 %0, %1, %2" : "=v"(r.u32[2]) : "v"(w.x), "v"(w.y));
  asm("v_cvt_pk_bf16_f32 %0, %1, %2" : "=v"(r.u32[3]) : "v"(w.z), "v"(w.w));
  return r.s;
}

// async global -> LDS, 16 B/lane (1 KB/wave), zero VGPR cost
__device__ __forceinline__ void gload16(const void* g, void* l){
  __builtin_amdgcn_global_load_lds(
      (const __attribute__((address_space(1))) void*)g,
      (__attribute__((address_space(3))) void*)l, 16, 0, 0);
}

// K0: y (f32, [n][k][s]) -> ybf (bf16 row-major [n][k][s]) and ytr (bf16 [n][s][k])
__global__ __launch_bounds__(256) void k_prep(const float* __restrict__ y,
                                              unsigned short* __restrict__ ybf,
                                              unsigned short* __restrict__ ytr){
  __shared__ unsigned short tile[64][72];
  int n  = blockIdx.x >> 6;                 // 64 s-tiles per batch
  int s0 = (blockIdx.x & 63) << 6;
  int tid = threadIdx.x;
  int k  = tid >> 2;
  int sc = (tid & 3) << 4;
  const float* yp = y + ((size_t)n * K_ + k) * HW_ + s0 + sc;
  union { unsigned short u16[16]; short8 s8[2]; uint4 q[2]; } u;
  u.s8[0] = cvt8(yp);
  u.s8[1] = cvt8(yp + 8);
  unsigned short* rp = ybf + ((size_t)n * K_ + k) * HW_ + s0 + sc;
  *(uint4*)rp       = u.q[0];
  *(uint4*)(rp + 8) = u.q[1];
#pragma unroll
  for (int j = 0; j < 16; ++j) tile[sc + j][k] = u.u16[j];
  __syncthreads();
  int s  = tid >> 2;
  int kc = (tid & 3) << 4;
  unsigned short* tp = ytr + ((size_t)n * HW_ + s0 + s) * K_ + kc;
  *(uint4*)tp       = *(const uint4*)&tile[s][kc];
  *(uint4*)(tp + 8) = *(const uint4*)&tile[s][kc + 8];
}

// K1: FUSED energy + softmax + PV + residual, c-split for 2 blocks/CU.
// Grid 512 = (n, 32 c-tiles, 2 c-halves) — softmax is per-c-row, so the
// c-split needs ZERO cross-block communication (R12/R14/R15 lesson: any
// global sync on the hot path loses).  512 thr (8 waves), 47 KB LDS ->
// 2 independent blocks/CU whose barriers stagger (the latency hiding the
// 1-block/CU fused design lacked).
//  Phase E: block owns 8 c-rows x full s; 32 chunks of 128 s, 2-buffer
//           gload_lds staging (w<4: 1 A + 2 B loads, vmcnt(3); w>=4: 2 B,
//           vmcnt(2)).  Wave (h=w>>2, q=w&3): s-half h, k-quad q; swapped
//           MFMA (A=y M=k, B=x N=c; cols 8-15 garbage, never stored).
//  Phase S: Els[2][8][64] reduce, softmax(-E), att -> swizzled attl
//           (rows 8-15 zeroed).
//  Phase P: wave w owns s in [w*512,+512); 8 groups of 64 s; 2-deep named
//           register pipeline; T[8][68] transpose (aliases drained staging)
//           -> 256B-contiguous x-load / out-store (2 rows-groups).
__global__ __launch_bounds__(512, 4) void k_fused(const float* __restrict__ x,
                                                  const unsigned short* __restrict__ ybf,
                                                  const unsigned short* __restrict__ ytr,
                                                  const float* __restrict__ scale,
                                                  float* __restrict__ out){
  __shared__ char stg[40960];       // 2 x (A 4KB | B 16KB); T aliases in phase P
  __shared__ float Els[2][8][64];   // 4 KB
  __shared__ char attl[2048];       // 16 c-rows x 64 k bf16 (8 valid), swizzled

  const int bid = ((blockIdx.x & 7) << 6) | (blockIdx.x >> 3);  // XCD swizzle (512%8==0)
  const int chf = bid & 1, ct = (bid >> 1) & 31, n = bid >> 6;  // XCD g == batch n
  const int tid = threadIdx.x;
  const int w = tid >> 6, l = tid & 63;
  const int lo = l & 15, hi = l >> 4;
  const int h = w >> 2, q = w & 3;
  const int c0 = (ct << 4) + (chf << 3);   // 8 c-rows per block

  float sc = scale[0];
  asm volatile("" :: "v"(sc));      // force completion: keep vmcnt counts clean

  // ---- Phase E staging addresses (chunk-invariant, pre-swizzled source) ----
  // A (waves 0-3): load rows {2w, 2w+1} (512B each) in one 1KB gload.
  const int ar = (w << 1) + (l >> 5);
  const char* asrc = (const char*)(x + ((size_t)n * C_ + c0 + (ar & 7)) * HW_)
                     + ((16 * (l & 31)) ^ ((ar & 7) << 4));
  // B (all waves): 2 loads, each 4 k-rows (256B each).
  const int kb0 = ((w << 1) + 0) * 4 + (l >> 4);
  const int kb1 = ((w << 1) + 1) * 4 + (l >> 4);
  const char* bsrc0 = (const char*)(ybf + ((size_t)n * K_ + kb0) * HW_)
                      + ((16 * (l & 15)) ^ ((kb0 & 7) << 4));
  const char* bsrc1 = (const char*)(ybf + ((size_t)n * K_ + kb1) * HW_)
                      + ((16 * (l & 15)) ^ ((kb1 & 7) << 4));

  floatx4 acc = {0.f, 0.f, 0.f, 0.f};
  const int aswz = (lo & 7) << 4;
  const int brow = (q << 4) + lo;   // brow&7 == lo&7

#define AS(BUF) (stg + (BUF) * 20480)
#define BS(BUF) (stg + (BUF) * 20480 + 4096)
#define STAGE(BUF, CH)                                                         \
  {                                                                            \
    if (w < 4)                                                                 \
      gload16(asrc  + (size_t)(CH) * (SCHUNK * 4), AS(BUF) + (w << 10));       \
    gload16(bsrc0 + (size_t)(CH) * (SCHUNK * 2), BS(BUF) + ((w << 1) << 10));  \
    gload16(bsrc1 + (size_t)(CH) * (SCHUNK * 2), BS(BUF) + (((w << 1) | 1) << 10)); \
  }

  STAGE(0, 0)

#pragma unroll
  for (int ch = 0; ch < NCH; ++ch){
    const int cur = ch & 1;
    if (ch + 1 < NCH){
      STAGE(cur ^ 1, ch + 1)
      if (w < 4) asm volatile("s_waitcnt vmcnt(3)" ::: "memory");
      else       asm volatile("s_waitcnt vmcnt(2)" ::: "memory");
    } else {
      asm volatile("s_waitcnt vmcnt(0)" ::: "memory");
    }
    __builtin_amdgcn_s_barrier();
    __builtin_amdgcn_sched_barrier(0);
#pragma unroll
    for (int ss = 0; ss < 2; ++ss){
      // wave's s-slice: s_local = h*64 + ss*32 + hi*8 (+j)
      int ao = (h << 8) + (ss << 7) + (hi << 5);       // f32 bytes
      const char* ab = AS(cur) + (lo << 9);            // row pitch 512B (lo>=8: junk)
      float4 a0f = *(const float4*)(ab + ((ao     ) ^ aswz));
      float4 a1f = *(const float4*)(ab + ((ao + 16) ^ aswz));
      union { unsigned u32[4]; short8 s; } af;
      asm("v_cvt_pk_bf16_f32 %0, %1, %2" : "=v"(af.u32[0]) : "v"(a0f.x), "v"(a0f.y));
      asm("v_cvt_pk_bf16_f32 %0, %1, %2" : "=v"(af.u32[1]) : "v"(a0f.z), "v"(a0f.w));
      asm("v_cvt_pk_bf16_f32 %0, %1, %2" : "=v"(af.u32[2]) : "v"(a1f.x), "v"(a1f.y));
      asm("v_cvt_pk_bf16_f32 %0, %1, %2" : "=v"(af.u32[3]) : "v"(a1f.z), "v"(a1f.w));
      int bo = (h << 7) + (ss << 6) + (hi << 4);       // bf16 bytes
      short8 bfr = *(const short8*)(BS(cur) + brow * 256 + (bo ^ aswz));
      // swapped: A = y-frag (M=k), B = x-frag (N=c) -> D col=lo->c, row->k
      acc = __builtin_amdgcn_mfma_f32_16x16x32_bf16(bfr, af.s, acc, 0, 0, 0);
    }
    __builtin_amdgcn_sched_barrier(0);
    __builtin_amdgcn_s_barrier();
  }
#undef STAGE

  // ---- Phase S: E partial [h][c=lo<8][k=q*16+hi*4+r] -> softmax ----
  if (lo < 8)
    *(floatx4*)&Els[h][lo][(q << 4) + (hi << 2)] = acc;
  __syncthreads();

  if (tid < 128){
    int c = tid >> 4, j = tid & 15;
    float4 t0 = *(const float4*)&Els[0][c][4 * j];
    float4 t1 = *(const float4*)&Els[1][c][4 * j];
    float e0 = t0.x + t1.x, e1 = t0.y + t1.y, e2 = t0.z + t1.z, e3 = t0.w + t1.w;
    float m = fminf(fminf(e0, e1), fminf(e2, e3));
#pragma unroll
    for (int off = 8; off; off >>= 1) m = fminf(m, __shfl_xor(m, off, 16));
    float p0 = __expf(m - e0), p1 = __expf(m - e1);
    float p2 = __expf(m - e2), p3 = __expf(m - e3);
    float s = p0 + p1 + p2 + p3;
#pragma unroll
    for (int off = 8; off; off >>= 1) s += __shfl_xor(s, off, 16);
    float inv = 1.f / s;
    unsigned d0, d1;
    asm("v_cvt_pk_bf16_f32 %0, %1, %2" : "=v"(d0) : "v"(p0 * inv), "v"(p1 * inv));
    asm("v_cvt_pk_bf16_f32 %0, %1, %2" : "=v"(d1) : "v"(p2 * inv), "v"(p3 * inv));
    uint2 dd; dd.x = d0; dd.y = d1;
    *(uint2*)(attl + c * 128 + ((8 * j) ^ ((c & 7) << 4))) = dd;
  } else if (tid < 256){
    int c = tid >> 4, j = tid & 15;                    // zero rows 8-15
    uint2 z; z.x = 0u; z.y = 0u;
    *(uint2*)(attl + c * 128 + ((8 * j) ^ ((c & 7) << 4))) = z;
  }
  __syncthreads();

  // ---- Phase P: PV + residual.  Wave w: s in [w*512, +512) ----
  short8 batt0 = *(const short8*)(attl + lo * 128 + ((     hi * 16) ^ ((lo & 7) << 4)));
  short8 batt1 = *(const short8*)(attl + lo * 128 + ((64 + hi * 16) ^ ((lo & 7) << 4)));
  const unsigned short* ybn = ytr + (size_t)n * HW_ * K_;
  const int sP = w << 9;
  float (*Tw)[68] = (float (*)[68])(stg + w * 2176);   // 8x68 f32, aliases staging
  size_t xb[2];
#pragma unroll
  for (int rg = 0; rg < 2; ++rg)
    xb[rg] = ((size_t)n * C_ + c0 + (rg << 2) + hi) * HW_ + sP + (lo << 2);

  short8 aA[8]; float4 xA[2];
  short8 aB[8]; float4 xB[2];

#define PVLOAD(G, AV, XV)                                                      \
  {                                                                            \
    int sg = sP + (G) * 64;                                                    \
    _Pragma("unroll")                                                          \
    for (int t = 0; t < 4; ++t){                                               \
      const unsigned short* ap = ybn + (size_t)(sg + t * 16 + lo) * K_ + (hi << 3); \
      AV[2 * t]     = *(const short8*)(ap);                                    \
      AV[2 * t + 1] = *(const short8*)(ap + 32);                               \
    }                                                                          \
    _Pragma("unroll")                                                          \
    for (int rg = 0; rg < 2; ++rg)                                             \
      XV[rg] = *(const float4*)(x + xb[rg] + (G) * 64);                        \
  }

#define PVCOMP(G, AV, XV)                                                      \
  {                                                                            \
    _Pragma("unroll")                                                          \
    for (int t = 0; t < 4; ++t){                                               \
      floatx4 a2 = {0.f, 0.f, 0.f, 0.f};                                       \
      a2 = __builtin_amdgcn_mfma_f32_16x16x32_bf16(AV[2 * t],     batt0, a2, 0, 0, 0); \
      a2 = __builtin_amdgcn_mfma_f32_16x16x32_bf16(AV[2 * t + 1], batt1, a2, 0, 0, 0); \
      if (lo < 8)                                                              \
        *(floatx4*)&Tw[lo][t * 16 + (hi << 2)] = a2;  /* D: col=lo->c, row->s */ \
    }                                                                          \
    _Pragma("unroll")                                                          \
    for (int rg = 0; rg < 2; ++rg){                                            \
      float4 v  = *(const float4*)&Tw[(rg << 2) + hi][lo << 2];                \
      float4 xv = XV[rg];                                                      \
      float4 o;                                                                \
      o.x = xv.x + sc * v.x; o.y = xv.y + sc * v.y;                            \
      o.z = xv.z + sc * v.z; o.w = xv.w + sc * v.w;                            \
      *(float4*)(out + xb[rg] + (G) * 64) = o;                                 \
    }                                                                          \
  }

  PVLOAD(0, aA, xA)
#pragma unroll
  for (int g = 0; g < 8; g += 2){
    PVLOAD(g + 1, aB, xB)
    PVCOMP(g, aA, xA)
    if (g + 2 < 8) PVLOAD(g + 2, aA, xA)
    PVCOMP(g + 1, aB, xB)
  }
#undef PVLOAD
#undef PVCOMP
#undef AS
#undef BS
}

extern "C" void kernel_launch(void* const* d_in, const int* in_sizes, int n_in,
                              void* d_out, int out_size, void* d_ws, size_t ws_size,
                              hipStream_t stream){
  const float* x     = (const float*)d_in[0];
  const float* y     = (const float*)d_in[1];
  const float* scale = (const float*)d_in[2];
  float* out = (float*)d_out;

  // ws layout (8 MiB total):
  //   ybf : N*K*HW bf16 = 4 MiB  @ 0
  //   ytr : N*HW*K bf16 = 4 MiB  @ 4 MiB
  char* ws = (char*)d_ws;
  unsigned short* ybf = (unsigned short*)(ws);
  unsigned short* ytr = (unsigned short*)(ws + (4u<<20));

  k_prep  <<<N_ * (HW_/64), 256, 0, stream>>>(y, ybf, ytr);
  k_fused <<<N_ * 32 * 2,   512, 0, stream>>>(x, ybf, ytr, scale, out);
}

// Round 17
// 49.003 us; speedup vs baseline: 3.1910x; 1.2956x over previous
//
#include <hip/hip_runtime.h>

// CCAMDec: out = x + scale * softmax(max_k(E)-E) @ y,  E = x·yᵀ over HW
// N=8, C=512, K=64, HW=4096. softmax(max-E) == softmax(-E) (shift invariance).
#define N_ 8
#define C_ 512
#define K_ 64
#define HW_ 4096
#define SCHUNK 128              // s per chunk
#define NCH 32                  // chunks (full s = 4096)

typedef __attribute__((ext_vector_type(8))) short short8;   // 8 bf16 (4 VGPRs) MFMA A/B frag
typedef __attribute__((ext_vector_type(4))) float floatx4;  // MFMA C/D frag

// 8 f32 -> 8 bf16 via hardware v_cvt_pk_bf16_f32 (RNE, 1 instr / 2 elems)
__device__ __forceinline__ short8 cvt8(const float* __restrict__ p){
  float4 u = *(const float4*)p;
  float4 w = *(const float4*)(p + 4);
  union { unsigned u32[4]; short8 s; } r;
  asm("v_cvt_pk_bf16_f32 %0, %1, %2" : "=v"(r.u32[0]) : "v"(u.x), "v"(u.y));
  asm("v_cvt_pk_bf16_f32 %0, %1, %2" : "=v"(r.u32[1]) : "v"(u.z), "v"(u.w));
  asm("v_cvt_pk_bf16_f32 %0, %1, %2" : "=v"(r.u32[2]) : "v"(w.x), "v"(w.y));
  asm("v_cvt_pk_bf16_f32 %0, %1, %2" : "=v"(r.u32[3]) : "v"(w.z), "v"(w.w));
  return r.s;
}

// async global -> LDS, 16 B/lane (1 KB/wave), zero VGPR cost
__device__ __forceinline__ void gload16(const void* g, void* l){
  __builtin_amdgcn_global_load_lds(
      (const __attribute__((address_space(1))) void*)g,
      (__attribute__((address_space(3))) void*)l, 16, 0, 0);
}

// K0: y (f32, [n][k][s]) -> ybf (bf16 row-major [n][k][s]) and ytr (bf16 [n][s][k])
__global__ __launch_bounds__(256) void k_prep(const float* __restrict__ y,
                                              unsigned short* __restrict__ ybf,
                                              unsigned short* __restrict__ ytr){
  __shared__ unsigned short tile[64][72];
  int n  = blockIdx.x >> 6;                 // 64 s-tiles per batch
  int s0 = (blockIdx.x & 63) << 6;
  int tid = threadIdx.x;
  int k  = tid >> 2;
  int sc = (tid & 3) << 4;
  const float* yp = y + ((size_t)n * K_ + k) * HW_ + s0 + sc;
  union { unsigned short u16[16]; short8 s8[2]; uint4 q[2]; } u;
  u.s8[0] = cvt8(yp);
  u.s8[1] = cvt8(yp + 8);
  unsigned short* rp = ybf + ((size_t)n * K_ + k) * HW_ + s0 + sc;
  *(uint4*)rp       = u.q[0];
  *(uint4*)(rp + 8) = u.q[1];
#pragma unroll
  for (int j = 0; j < 16; ++j) tile[sc + j][k] = u.u16[j];
  __syncthreads();
  int s  = tid >> 2;
  int kc = (tid & 3) << 4;
  unsigned short* tp = ytr + ((size_t)n * HW_ + s0 + s) * K_ + kc;
  *(uint4*)tp       = *(const uint4*)&tile[s][kc];
  *(uint4*)(tp + 8) = *(const uint4*)&tile[s][kc + 8];
}

// K1: FUSED energy + softmax + PV + residual, BARRIER-FREE phase E.
// Grid 256 (1 block/CU), 1024 thr (16 waves).  Block = (n,16c), full s.
//  Phase E: wave (h=w>>2, q=w&3) owns s-slice [h*32,+32) of each 128-s chunk
//           and k-quad q.  Staging is WAVE-PRIVATE (wave consumes only what
//           it stages): per chunk 2 A-gloads (16 c-rows x 128B, x dup 4x
//           across q-waves -> L2-served) + 1 B-gload (16 k-rows x 64B) into
//           a private 3KB double-buffer.  Per-row granule-XOR pre-swizzle on
//           the source, same XOR on read.  ZERO barriers in the chunk loop —
//           only per-wave vmcnt(3) -> 16 independent load streams per CU.
//  Phase S: one __syncthreads; Els[4][16][64] reduce over h; softmax(-E);
//           att -> XOR-swizzled attl.
//  Phase P: wave w owns s in [w*256,+256); 2-deep named register pipeline;
//           T[16][68] transpose (aliases drained staging) -> 256B-contiguous
//           x-load(L3-hot)/out-store.  (Already wave-independent.)
// LDS 114 KB: stg 96K (16 waves x 6K) | Els 16K | attl 2K; T aliases stg.
__global__ __launch_bounds__(1024) void k_fused(const float* __restrict__ x,
                                                const unsigned short* __restrict__ ybf,
                                                const unsigned short* __restrict__ ytr,
                                                const float* __restrict__ scale,
                                                float* __restrict__ out){
  __shared__ char smem[116736];

  const int bid = ((blockIdx.x & 7) << 5) | (blockIdx.x >> 3);  // XCD swizzle (256%8==0)
  const int ct = bid & 31, n = bid >> 5;
  const int tid = threadIdx.x;
  const int w = tid >> 6, l = tid & 63;
  const int lo = l & 15, hi = l >> 4;
  const int h = w >> 2, q = w & 3;
  const int c0 = ct << 4;

  float sc = scale[0];
  asm volatile("" :: "v"(sc));      // force completion: keep vmcnt counts clean

  // ---- Phase E per-lane source addresses (chunk-invariant, pre-swizzled) ----
  // A gload g (g=0,1): row r = g*8 + (l>>3); stored 16B-granule (l&7) holds
  // true s-granule (l&7)^(r&7), r&7 = l>>3.
  const int ar = l >> 3;
  const int ag = (l & 7) ^ ar;                       // true s-granule (4 f32)
  const char* asrc0 = (const char*)(x + ((size_t)n * C_ + c0 + 0 + ar) * HW_
                                    + h * 32 + ag * 4);
  const char* asrc1 = (const char*)(x + ((size_t)n * C_ + c0 + 8 + ar) * HW_
                                    + h * 32 + ag * 4);
  // B gload: row r = l>>2 (k = q*16+r); stored granule (l&3) holds true
  // s-granule (l&3)^(r&3) (16B = 8 bf16).
  const int br = l >> 2;
  const int bg = (l & 3) ^ (br & 3);
  const char* bsrc = (const char*)(ybf + ((size_t)n * K_ + (q << 4) + br) * HW_
                                   + h * 32 + bg * 8);

  char* wbase = smem + w * 6144;    // wave-private: [2 bufs][A 2K | B 1K]
  floatx4 acc = {0.f, 0.f, 0.f, 0.f};

#define ESTG(BUF, CH)                                                          \
  {                                                                            \
    gload16(asrc0 + (size_t)(CH) * (SCHUNK * 4), wbase + (BUF) * 3072);        \
    gload16(asrc1 + (size_t)(CH) * (SCHUNK * 4), wbase + (BUF) * 3072 + 1024); \
    gload16(bsrc  + (size_t)(CH) * (SCHUNK * 2), wbase + (BUF) * 3072 + 2048); \
  }

#define ECMP(BUF)                                                              \
  {                                                                            \
    const char* Ab = wbase + (BUF) * 3072;                                     \
    float4 f0 = *(const float4*)(Ab + lo * 128 + (((hi << 1)       ^ (lo & 7)) << 4)); \
    float4 f1 = *(const float4*)(Ab + lo * 128 + ((((hi << 1) | 1) ^ (lo & 7)) << 4)); \
    union { unsigned u32[4]; short8 s; } xf;                                   \
    asm("v_cvt_pk_bf16_f32 %0, %1, %2" : "=v"(xf.u32[0]) : "v"(f0.x), "v"(f0.y)); \
    asm("v_cvt_pk_bf16_f32 %0, %1, %2" : "=v"(xf.u32[1]) : "v"(f0.z), "v"(f0.w)); \
    asm("v_cvt_pk_bf16_f32 %0, %1, %2" : "=v"(xf.u32[2]) : "v"(f1.x), "v"(f1.y)); \
    asm("v_cvt_pk_bf16_f32 %0, %1, %2" : "=v"(xf.u32[3]) : "v"(f1.z), "v"(f1.w)); \
    short8 yf = *(const short8*)(Ab + 2048 + lo * 64 + ((hi ^ (lo & 3)) << 4)); \
    /* swapped: A = y-frag (M=k), B = x-frag (N=c) -> D col=lo->c, row->k */   \
    acc = __builtin_amdgcn_mfma_f32_16x16x32_bf16(yf, xf.s, acc, 0, 0, 0);     \
  }

  ESTG(0, 0) ESTG(1, 1)            // 6 loads in flight

  for (int cp = 0; cp < 15; ++cp){
    int ch = cp << 1;
    asm volatile("s_waitcnt vmcnt(3)" ::: "memory");   // chunk ch ready
    ECMP(0)
    ESTG(0, ch + 2)
    asm volatile("s_waitcnt vmcnt(3)" ::: "memory");   // chunk ch+1 ready
    ECMP(1)
    ESTG(1, ch + 3)
  }
  asm volatile("s_waitcnt vmcnt(3)" ::: "memory");     // ch=30
  ECMP(0)
  asm volatile("s_waitcnt vmcnt(0)" ::: "memory");     // ch=31
  ECMP(1)
#undef ESTG
#undef ECMP

  // ---- Phase S: E partial [h][c=lo][k=q*16+hi*4+r] -> softmax ----
  float (*Els)[16][64] = (float (*)[16][64])(smem + 98304);
  *(floatx4*)&Els[h][lo][(q << 4) + (hi << 2)] = acc;
  __syncthreads();

  char* attl = smem + 114688;       // att 16c x 64k bf16, XOR-swizzled
  if (tid < 256){
    int c = tid >> 4, j = tid & 15;
    float4 t0 = *(const float4*)&Els[0][c][4 * j];
    float4 t1 = *(const float4*)&Els[1][c][4 * j];
    float4 t2 = *(const float4*)&Els[2][c][4 * j];
    float4 t3 = *(const float4*)&Els[3][c][4 * j];
    float e0 = t0.x + t1.x + t2.x + t3.x;
    float e1 = t0.y + t1.y + t2.y + t3.y;
    float e2 = t0.z + t1.z + t2.z + t3.z;
    float e3 = t0.w + t1.w + t2.w + t3.w;
    float m = fminf(fminf(e0, e1), fminf(e2, e3));
#pragma unroll
    for (int off = 8; off; off >>= 1) m = fminf(m, __shfl_xor(m, off, 16));
    float p0 = __expf(m - e0), p1 = __expf(m - e1);
    float p2 = __expf(m - e2), p3 = __expf(m - e3);
    float s = p0 + p1 + p2 + p3;
#pragma unroll
    for (int off = 8; off; off >>= 1) s += __shfl_xor(s, off, 16);
    float inv = 1.f / s;
    unsigned d0, d1;
    asm("v_cvt_pk_bf16_f32 %0, %1, %2" : "=v"(d0) : "v"(p0 * inv), "v"(p1 * inv));
    asm("v_cvt_pk_bf16_f32 %0, %1, %2" : "=v"(d1) : "v"(p2 * inv), "v"(p3 * inv));
    uint2 dd; dd.x = d0; dd.y = d1;
    *(uint2*)(attl + c * 128 + ((8 * j) ^ ((c & 7) << 4))) = dd;
  }
  __syncthreads();

  // ---- Phase P: PV + residual.  Wave w: s in [w*256, (w+1)*256) ----
  short8 batt0 = *(const short8*)(attl + lo * 128 + ((     hi * 16) ^ ((lo & 7) << 4)));
  short8 batt1 = *(const short8*)(attl + lo * 128 + ((64 + hi * 16) ^ ((lo & 7) << 4)));
  const unsigned short* ybn = ytr + (size_t)n * HW_ * K_;
  const int sP = w << 8;
  float (*Tw)[68] = (float (*)[68])(smem + w * 4352);   // alias staging (drained)
  size_t xb[4];
#pragma unroll
  for (int rg = 0; rg < 4; ++rg)
    xb[rg] = ((size_t)n * C_ + c0 + (rg << 2) + hi) * HW_ + sP + (lo << 2);

  short8 aA[8]; float4 xA[4];
  short8 aB[8]; float4 xB[4];

#define PVLOAD(G, AV, XV)                                                      \
  {                                                                            \
    int sg = sP + (G) * 64;                                                    \
    _Pragma("unroll")                                                          \
    for (int t = 0; t < 4; ++t){                                               \
      const unsigned short* ap = ybn + (size_t)(sg + t * 16 + lo) * K_ + (hi << 3); \
      AV[2 * t]     = *(const short8*)(ap);                                    \
      AV[2 * t + 1] = *(const short8*)(ap + 32);                               \
    }                                                                          \
    _Pragma("unroll")                                                          \
    for (int rg = 0; rg < 4; ++rg)                                             \
      XV[rg] = *(const float4*)(x + xb[rg] + (G) * 64);                        \
  }

#define PVCOMP(G, AV, XV)                                                      \
  {                                                                            \
    _Pragma("unroll")                                                          \
    for (int t = 0; t < 4; ++t){                                               \
      floatx4 a2 = {0.f, 0.f, 0.f, 0.f};                                       \
      a2 = __builtin_amdgcn_mfma_f32_16x16x32_bf16(AV[2 * t],     batt0, a2, 0, 0, 0); \
      a2 = __builtin_amdgcn_mfma_f32_16x16x32_bf16(AV[2 * t + 1], batt1, a2, 0, 0, 0); \
      *(floatx4*)&Tw[lo][t * 16 + (hi << 2)] = a2;   /* D: col=lo->c, row->s */ \
    }                                                                          \
    _Pragma("unroll")                                                          \
    for (int rg = 0; rg < 4; ++rg){                                            \
      float4 v  = *(const float4*)&Tw[(rg << 2) + hi][lo << 2];                \
      float4 xv = XV[rg];                                                      \
      float4 o;                                                                \
      o.x = xv.x + sc * v.x; o.y = xv.y + sc * v.y;                            \
      o.z = xv.z + sc * v.z; o.w = xv.w + sc * v.w;                            \
      *(float4*)(out + xb[rg] + (G) * 64) = o;                                 \
    }                                                                          \
  }

  PVLOAD(0, aA, xA)
  PVLOAD(1, aB, xB)
  PVCOMP(0, aA, xA)
  PVLOAD(2, aA, xA)
  PVCOMP(1, aB, xB)
  PVLOAD(3, aB, xB)
  PVCOMP(2, aA, xA)
  PVCOMP(3, aB, xB)
#undef PVLOAD
#undef PVCOMP
}

extern "C" void kernel_launch(void* const* d_in, const int* in_sizes, int n_in,
                              void* d_out, int out_size, void* d_ws, size_t ws_size,
                              hipStream_t stream){
  const float* x     = (const float*)d_in[0];
  const float* y     = (const float*)d_in[1];
  const float* scale = (const float*)d_in[2];
  float* out = (float*)d_out;

  // ws layout (8 MiB total):
  //   ybf : N*K*HW bf16 = 4 MiB  @ 0
  //   ytr : N*HW*K bf16 = 4 MiB  @ 4 MiB
  char* ws = (char*)d_ws;
  unsigned short* ybf = (unsigned short*)(ws);
  unsigned short* ytr = (unsigned short*)(ws + (4u<<20));

  k_prep  <<<N_ * (HW_/64), 256,  0, stream>>>(y, ybf, ytr);
  k_fused <<<N_ * 32,       1024, 0, stream>>>(x, ybf, ytr, scale, out);
}